// Round 5
// baseline (2175.940 us; speedup 1.0000x reference)
//
#include <hip/hip_runtime.h>
#include <hip/hip_bf16.h>

#define TSTEPS 20
#define NBLK 256

typedef __bf16 bf16x8 __attribute__((ext_vector_type(8)));
typedef float f32x4 __attribute__((ext_vector_type(4)));
typedef unsigned short u16;

__device__ __forceinline__ u16 f2bf(float f) {
  unsigned u = __builtin_bit_cast(unsigned, f);
  u = (u + 0x7FFFu + ((u >> 16) & 1u)) >> 16;  // RNE
  return (u16)u;
}
__device__ __forceinline__ float sig_(float v) { return 1.f / (1.f + __expf(-v)); }
__device__ __forceinline__ float tanh_(float v) { return 1.f - 2.f / (1.f + __expf(2.f * v)); }

#define MFMA16(a, b, c) __builtin_amdgcn_mfma_f32_16x16x32_bf16((a), (b), (c), 0, 0, 0)
#define BAR() asm volatile("s_barrier" ::: "memory")
#define WAITV0() asm volatile("s_waitcnt vmcnt(0)" ::: "memory")
#define WAITV4() asm volatile("s_waitcnt vmcnt(4)" ::: "memory")
#define WAITV6() asm volatile("s_waitcnt vmcnt(6)" ::: "memory")

__device__ __forceinline__ void gload16(const u16* g, u16* lds) {
#if defined(__HIP_DEVICE_COMPILE__)
  __builtin_amdgcn_global_load_lds(
      (const __attribute__((address_space(1))) unsigned*)g,
      (__attribute__((address_space(3))) unsigned*)lds, 16, 0, 0);
#endif
}

// ---------------- prep kernels ----------------
__global__ void convert_f32_bf16(const float* __restrict__ s, u16* __restrict__ d, int n) {
  int i = (blockIdx.x * blockDim.x + threadIdx.x) * 4;
  if (i + 3 < n) {
    float4 v = *reinterpret_cast<const float4*>(s + i);
    ushort4 o;
    o.x = f2bf(v.x); o.y = f2bf(v.y); o.z = f2bf(v.z); o.w = f2bf(v.w);
    *reinterpret_cast<ushort4*>(d + i) = o;
  }
}

// permuted Whh: p = slab*256 + wn*64 + f*16 + jl  <-  orig row f*512 + slab*64 + wn*16 + jl
__global__ void convert_whh_p(const float* __restrict__ w, u16* __restrict__ d) {
  int p = blockIdx.x;         // 2048 rows
  int k = threadIdx.x;        // 512 cols
  int jl = p & 15, f = (p >> 4) & 3, wn = (p >> 6) & 3, slab = p >> 8;
  int orig = (f << 9) + (slab << 6) + (wn << 4) + jl;
  d[p * 512 + k] = f2bf(w[orig * 512 + k]);
}

__global__ void init_state(const float* __restrict__ h0, u16* __restrict__ hbf,
                           int* __restrict__ cnt, int n) {
  int i = blockIdx.x * blockDim.x + threadIdx.x;
  if (i < n) hbf[i] = f2bf(h0[i]);
  if (i == 0) *cnt = 0;
}

// ---------------- persistent fused kernel ----------------
// 256 blocks x 512 threads, 1 block/CU (VGPR-forced). Per iteration i (0..20):
//   i<20: LSTM step i   : block tile 256n x 256gc (4g x 64u), K=512, BK=32 dbuf
//   i>0 : FC1 for t=i-1 : block tile 128m x 64j,  K=1024, BK=64 dbuf (reads same h)
//   grid spin-barrier between iterations.
__global__ __launch_bounds__(512, 1) void lstm_persist(
    const u16* __restrict__ Wp,     // [2048][512] permuted bf16
    const float* __restrict__ Wih,  // [2048][2]
    const float* __restrict__ bih, const float* __restrict__ bhh,
    const float* __restrict__ x,    // [8192][20][2]
    const float* __restrict__ c0,   // [8192][512]
    u16* __restrict__ hb0,          // [8192][512] bf16 (= h0 at entry)
    u16* __restrict__ hb1,
    const u16* __restrict__ fc1w,   // [512][20480] bf16
    float* __restrict__ faccg,      // [4096][512]
    int* __restrict__ cnt) {
  __shared__ u16 smem[32768];       // 64 KB: 4 slots of 8192 u16 (LA0 LB0 | LA1 LB1)

  const int tid = threadIdx.x;
  const int lane = tid & 63, wid = tid >> 6;
  const int jl = lane & 15, kg = lane >> 4;
  const int wm = wid >> 2, wn = wid & 3;       // LSTM: 2M x 4N waves
  const int bid = blockIdx.x;
  const int slab = bid & 7;                    // gc-slab == XCD (L2-resident B slice)
  const int n0 = (bid >> 3) * 256;
  const int brow0 = slab * 256;
  const int u = slab * 64 + wn * 16 + jl;
  const int Fm0 = (bid >> 3) * 128;            // fc1 tile
  const int Fj0 = slab * 64;
  const int Fwm = wid >> 1, Fwn = wid & 1;     // fc1: 4M x 2N waves

  // staging thread->slot maps
  const int rL4 = tid >> 2, ch4 = tid & 3;                       // 64B rows (BK=32)
  const int sw4 = ch4 ^ (rL4 & 3) ^ ((rL4 >> 2) & 3);
  const int rL8 = tid >> 3, ch8 = tid & 7;                       // 128B rows (BK=64)
  const int sw8 = ch8 ^ (rL8 & 7);

  // ---- persistent state ----
  f32x4 creg[8];
#pragma unroll
  for (int mt = 0; mt < 8; ++mt)
#pragma unroll
    for (int r = 0; r < 4; ++r) {
      int n = n0 + wm * 128 + mt * 16 + kg * 4 + r;
      creg[mt][r] = c0[n * 512 + u];
    }
  f32x4 facc[2][2];
#pragma unroll
  for (int a = 0; a < 2; ++a)
#pragma unroll
    for (int b = 0; b < 2; ++b) facc[a][b] = (f32x4){0.f, 0.f, 0.f, 0.f};

  for (int i = 0; i <= TSTEPS; ++i) {
    const u16* hcur = (i & 1) ? hb1 : hb0;
    u16* hnxt = (i & 1) ? hb0 : hb1;

    if (i < TSTEPS) {
      // ================= LSTM step i =================
      f32x4 acc[8][4];
#pragma unroll
      for (int mt = 0; mt < 8; ++mt)
#pragma unroll
        for (int f = 0; f < 4; ++f) acc[mt][f] = (f32x4){0.f, 0.f, 0.f, 0.f};

      // prologue: stage K-tile 0 -> parity 0
#pragma unroll
      for (int q = 0; q < 2; ++q) {
        int r = q * 128 + rL4;
        int sw = ch4 ^ (r & 3) ^ ((r >> 2) & 3);
        gload16(hcur + (n0 + r) * 512 + sw * 8, smem + q * 4096 + wid * 512);
        gload16(Wp + (brow0 + r) * 512 + sw * 8, smem + 8192 + q * 4096 + wid * 512);
      }
#pragma unroll 1
      for (int it = 0; it < 16; ++it) {
        if (it < 15) {
          const int kn = (it + 1) * 32;
          u16* dst = smem + ((it + 1) & 1) * 16384;
#pragma unroll
          for (int q = 0; q < 2; ++q) {
            int r = q * 128 + rL4;
            int sw = ch4 ^ (r & 3) ^ ((r >> 2) & 3);
            gload16(hcur + (n0 + r) * 512 + kn + sw * 8, dst + q * 4096 + wid * 512);
            gload16(Wp + (brow0 + r) * 512 + kn + sw * 8, dst + 8192 + q * 4096 + wid * 512);
          }
          WAITV4();
        } else {
          WAITV0();
        }
        BAR();
        const u16* LA = smem + (it & 1) * 16384;
        const u16* LB = LA + 8192;
        bf16x8 a[8], b[4];
#pragma unroll
        for (int mt = 0; mt < 8; ++mt) {
          int rr = wm * 128 + mt * 16 + jl;
          int cc = kg ^ (rr & 3) ^ ((rr >> 2) & 3);
          a[mt] = *reinterpret_cast<const bf16x8*>(LA + rr * 32 + cc * 8);
        }
#pragma unroll
        for (int f = 0; f < 4; ++f) {
          int rr = wn * 64 + f * 16 + jl;
          int cc = kg ^ (rr & 3) ^ ((rr >> 2) & 3);
          b[f] = *reinterpret_cast<const bf16x8*>(LB + rr * 32 + cc * 8);
        }
#pragma unroll
        for (int mt = 0; mt < 8; ++mt)
#pragma unroll
          for (int f = 0; f < 4; ++f) acc[mt][f] = MFMA16(a[mt], b[f], acc[mt][f]);
        BAR();
      }

      // ---- activation epilogue (per-lane: all 4 gates of (n,u)) ----
      float eb[4], w0[4], w1[4];
#pragma unroll
      for (int f = 0; f < 4; ++f) {
        int j = f * 512 + u;
        eb[f] = bih[j] + bhh[j];
        w0[f] = Wih[j * 2 + 0];
        w1[f] = Wih[j * 2 + 1];
      }
#pragma unroll
      for (int mt = 0; mt < 8; ++mt)
#pragma unroll
        for (int r = 0; r < 4; ++r) {
          int n = n0 + wm * 128 + mt * 16 + kg * 4 + r;
          float x0 = x[n * 40 + i * 2 + 0];
          float x1 = x[n * 40 + i * 2 + 1];
          float gi = acc[mt][0][r] + eb[0] + x0 * w0[0] + x1 * w1[0];
          float gf = acc[mt][1][r] + eb[1] + x0 * w0[1] + x1 * w1[1];
          float gg = acc[mt][2][r] + eb[2] + x0 * w0[2] + x1 * w1[2];
          float go = acc[mt][3][r] + eb[3] + x0 * w0[3] + x1 * w1[3];
          float iv = sig_(gi), fv = sig_(gf), gv = tanh_(gg), ov = sig_(go);
          float cn = fv * creg[mt][r] + iv * gv;
          creg[mt][r] = cn;
          hnxt[n * 512 + u] = f2bf(ov * tanh_(cn));
        }
    }

    if (i > 0) {
      // ================= FC1 accumulate, t = i-1, A = h(i) = hcur =================
      const int t = i - 1;
      const long jrow = (long)(Fj0 + Fwn * 32 + jl) * 20480 + (long)t * 512;
      bf16x8 bbA[2][2], bbB[2][2];
      // prologue: stage A K-tile 0 -> parity 0; load B frags k0=0
#pragma unroll
      for (int q = 0; q < 2; ++q) {
        int r = q * 64 + rL8;
        int sw = ch8 ^ (r & 7);
        gload16(hcur + (2 * (Fm0 + r)) * 512 + sw * 8, smem + q * 4096 + wid * 512);
      }
#pragma unroll
      for (int jf = 0; jf < 2; ++jf)
#pragma unroll
        for (int ks = 0; ks < 2; ++ks)
          bbA[jf][ks] = *reinterpret_cast<const bf16x8*>(
              fc1w + jrow + jf * 16 * 20480 + ks * 32 + kg * 8);

      auto fbody = [&](int it, bf16x8 (&bc)[2][2], bf16x8 (&bn)[2][2]) {
        if (it < 15) {
          const int kn = (it + 1) * 64;
          const int an = kn >> 9, hcn = kn & 511;
          u16* dst = smem + ((it + 1) & 1) * 16384;
#pragma unroll
          for (int q = 0; q < 2; ++q) {
            int r = q * 64 + rL8;
            int sw = ch8 ^ (r & 7);
            gload16(hcur + (2 * (Fm0 + r) + an) * 512 + hcn + sw * 8,
                    dst + q * 4096 + wid * 512);
          }
#pragma unroll
          for (int jf = 0; jf < 2; ++jf)
#pragma unroll
            for (int ks = 0; ks < 2; ++ks)
              bn[jf][ks] = *reinterpret_cast<const bf16x8*>(
                  fc1w + jrow + an * 10240 + jf * 16 * 20480 + hcn + ks * 32 + kg * 8);
          WAITV6();
        } else {
          WAITV0();
        }
        BAR();
        const u16* FB = smem + (it & 1) * 16384;
        bf16x8 af[2][2];
#pragma unroll
        for (int mf = 0; mf < 2; ++mf) {
          int rr = Fwm * 32 + mf * 16 + jl;
#pragma unroll
          for (int ks = 0; ks < 2; ++ks) {
            int cc = (ks * 4 + kg) ^ (rr & 7);
            af[mf][ks] = *reinterpret_cast<const bf16x8*>(FB + rr * 64 + cc * 8);
          }
        }
#pragma unroll
        for (int mf = 0; mf < 2; ++mf)
#pragma unroll
          for (int jf = 0; jf < 2; ++jf)
#pragma unroll
            for (int ks = 0; ks < 2; ++ks)
              facc[mf][jf] = MFMA16(af[mf][ks], bc[jf][ks], facc[mf][jf]);
        BAR();
      };
#pragma unroll 1
      for (int it2 = 0; it2 < 8; ++it2) {
        fbody(it2 * 2, bbA, bbB);
        fbody(it2 * 2 + 1, bbB, bbA);
      }
    }

    // ---- grid barrier (h(i+1) must be globally visible) ----
    if (i < TSTEPS) {
      __syncthreads();
      if (tid == 0) {
        __threadfence();
        __hip_atomic_fetch_add(cnt, 1, __ATOMIC_ACQ_REL, __HIP_MEMORY_SCOPE_AGENT);
        const int tgt = NBLK * (i + 1);
        while (__hip_atomic_load(cnt, __ATOMIC_ACQUIRE, __HIP_MEMORY_SCOPE_AGENT) < tgt)
          __builtin_amdgcn_s_sleep(16);
      }
      __syncthreads();
      __threadfence();
    }
  }

  // ---- write facc to global for head kernel ----
#pragma unroll
  for (int mf = 0; mf < 2; ++mf)
#pragma unroll
    for (int jf = 0; jf < 2; ++jf) {
      int j = Fj0 + Fwn * 32 + jf * 16 + jl;
#pragma unroll
      for (int r = 0; r < 4; ++r) {
        int m = Fm0 + Fwm * 32 + mf * 16 + kg * 4 + r;
        faccg[m * 512 + j] = facc[mf][jf][r];
      }
    }
}

// ---------------- head: relu(facc + b1) @ fc2^T + b2, sigmoid ----------------
__global__ __launch_bounds__(256) void head_kernel(
    const float* __restrict__ acc, const float* __restrict__ fc1b,
    const float* __restrict__ fc2w, const float* __restrict__ fc2b,
    float* __restrict__ out) {
  int lane = threadIdx.x & 63;
  int row = blockIdx.x * 4 + (threadIdx.x >> 6);
  float s = 0.f;
#pragma unroll
  for (int j = lane; j < 512; j += 64)
    s += fmaxf(acc[row * 512 + j] + fc1b[j], 0.f) * fc2w[j];
#pragma unroll
  for (int off = 32; off; off >>= 1) s += __shfl_down(s, off);
  if (lane == 0) out[row] = 1.f / (1.f + __expf(-(s + fc2b[0])));
}

extern "C" void kernel_launch(void* const* d_in, const int* in_sizes, int n_in,
                              void* d_out, int out_size, void* d_ws, size_t ws_size,
                              hipStream_t stream) {
  const float* x = (const float*)d_in[0];
  const float* h0 = (const float*)d_in[2];
  const float* c0 = (const float*)d_in[3];
  const float* Wih = (const float*)d_in[4];
  const float* Whh = (const float*)d_in[5];
  const float* bih = (const float*)d_in[6];
  const float* bhh = (const float*)d_in[7];
  const float* fc1w = (const float*)d_in[8];
  const float* fc1b = (const float*)d_in[9];
  const float* fc2w = (const float*)d_in[10];
  const float* fc2b = (const float*)d_in[11];
  float* out = (float*)d_out;

  char* ws = (char*)d_ws;
  const size_t MB = 1 << 20;
  u16* Whh_p = (u16*)(ws);               //  2 MB
  u16* fc1_bf = (u16*)(ws + 2 * MB);     // 20 MB
  u16* hbf0 = (u16*)(ws + 22 * MB);      //  8 MB
  u16* hbf1 = (u16*)(ws + 30 * MB);      //  8 MB
  float* facc = (float*)(ws + 38 * MB);  //  8 MB
  int* cnt = (int*)(ws + 46 * MB);

  convert_whh_p<<<2048, 512, 0, stream>>>(Whh, Whh_p);
  convert_f32_bf16<<<10240, 256, 0, stream>>>(fc1w, fc1_bf, 512 * 20480);
  init_state<<<16384, 256, 0, stream>>>(h0, hbf0, cnt, 8192 * 512);

  lstm_persist<<<NBLK, 512, 0, stream>>>(Whh_p, Wih, bih, bhh, x, c0,
                                         hbf0, hbf1, fc1_bf, facc, cnt);
  head_kernel<<<1024, 256, 0, stream>>>(facc, fc1b, fc2w, fc2b, out);
}

// Round 6
// 1778.942 us; speedup vs baseline: 1.2232x; 1.2232x over previous
//
#include <hip/hip_runtime.h>
#include <hip/hip_bf16.h>

#define TSTEPS 20
#define NBLK 256
#define SMEM_BYTES 131072

typedef __bf16 bf16x8 __attribute__((ext_vector_type(8)));
typedef float f32x4 __attribute__((ext_vector_type(4)));
typedef unsigned short u16;

__device__ __forceinline__ u16 f2bf(float f) {
  unsigned u = __builtin_bit_cast(unsigned, f);
  u = (u + 0x7FFFu + ((u >> 16) & 1u)) >> 16;  // RNE
  return (u16)u;
}
__device__ __forceinline__ float sig_(float v) { return 1.f / (1.f + __expf(-v)); }
__device__ __forceinline__ float tanh_(float v) { return 1.f - 2.f / (1.f + __expf(2.f * v)); }

#define MFMA16(a, b, c) __builtin_amdgcn_mfma_f32_16x16x32_bf16((a), (b), (c), 0, 0, 0)
#define BAR() asm volatile("s_barrier" ::: "memory")
#define WAITV0() asm volatile("s_waitcnt vmcnt(0)" ::: "memory")
#define WAITV3() asm volatile("s_waitcnt vmcnt(3)" ::: "memory")
#define WAITV8() asm volatile("s_waitcnt vmcnt(8)" ::: "memory")

__device__ __forceinline__ void gload16(const u16* g, u16* lds) {
#if defined(__HIP_DEVICE_COMPILE__)
  __builtin_amdgcn_global_load_lds(
      (const __attribute__((address_space(1))) unsigned*)g,
      (__attribute__((address_space(3))) unsigned*)lds, 16, 0, 0);
#endif
}

// ---------------- prep kernels ----------------
__global__ void convert_f32_bf16(const float* __restrict__ s, u16* __restrict__ d, int n) {
  int i = (blockIdx.x * blockDim.x + threadIdx.x) * 4;
  if (i + 3 < n) {
    float4 v = *reinterpret_cast<const float4*>(s + i);
    ushort4 o;
    o.x = f2bf(v.x); o.y = f2bf(v.y); o.z = f2bf(v.z); o.w = f2bf(v.w);
    *reinterpret_cast<ushort4*>(d + i) = o;
  }
}

// permuted Whh: p = slab*256 + wn*64 + f*16 + jl  <-  orig row f*512 + slab*64 + wn*16 + jl
__global__ void convert_whh_p(const float* __restrict__ w, u16* __restrict__ d) {
  int p = blockIdx.x;         // 2048 rows
  int k = threadIdx.x;        // 512 cols
  int jl = p & 15, f = (p >> 4) & 3, wn = (p >> 6) & 3, slab = p >> 8;
  int orig = (f << 9) + (slab << 6) + (wn << 4) + jl;
  d[p * 512 + k] = f2bf(w[orig * 512 + k]);
}

__global__ void init_state(const float* __restrict__ h0, u16* __restrict__ hbf,
                           int* __restrict__ cnt, int n) {
  int i = blockIdx.x * blockDim.x + threadIdx.x;
  if (i < n) hbf[i] = f2bf(h0[i]);
  if (i < 1024) cnt[i] = 0;
}

// ---------------- persistent fused kernel ----------------
// 256 blocks x 512 threads, 1 block/CU (VGPR capacity forces co-residency,
// so the spin barriers cannot deadlock). bid -> (xcd=bid&7, slab, q):
// group gg = xcd*4+q owns n-rows [gg*256, gg*256+256); its 8 slab-blocks all
// have the same bid%8 -> same XCD (heuristic; perf-only). Sync is PER-GROUP.
// Per iteration i: LSTM step i (i<20) then FC1 for t=i-1 (i>0), both reading
// h(i); c-state and fc1 accumulator live in registers for all 20 steps.
__global__ __launch_bounds__(512, 1) void lstm_persist(
    const u16* __restrict__ Wp,     // [2048][512] permuted bf16
    const float* __restrict__ Wih,  // [2048][2]
    const float* __restrict__ bih, const float* __restrict__ bhh,
    const float* __restrict__ x,    // [8192][20][2]
    const float* __restrict__ c0,   // [8192][512]
    u16* __restrict__ hb0,          // [8192][512] bf16 (= h0 at entry)
    u16* __restrict__ hb1,
    const u16* __restrict__ fc1w,   // [512][20480] bf16
    float* __restrict__ faccg,      // [4096][512]
    int* __restrict__ cnt) {
  extern __shared__ u16 smem[];     // 128 KB: 2 x (A[256][64] + B[256][64])

  const int tid = threadIdx.x;
  const int lane = tid & 63, wid = tid >> 6;
  const int jl = lane & 15, kg = lane >> 4;
  const int wm = wid >> 2, wn = wid & 3;       // LSTM: 2M x 4N waves
  const int bid = blockIdx.x;
  const int xcd = bid & 7;
  const int slab = (bid >> 3) & 7;
  const int q = bid >> 6;
  const int gg = xcd * 4 + q;                  // n-group 0..31
  const int n0 = gg * 256;
  const int brow0 = slab * 256;
  const int u = slab * 64 + wn * 16 + jl;
  const int Fm0 = gg * 128;                    // fc1 tile
  const int Fj0 = slab * 64;
  const int Fwm = wid >> 1, Fwn = wid & 1;     // fc1: 4M x 2N waves
  int* gcnt = cnt + gg * 32;                   // 128B-spaced counter

  // staging maps: 128B rows, 8 chunks of 16B, XOR-swizzled source chunk
  const int rL = tid >> 3;                     // row within 64-row round
  const int sw = (tid & 7) ^ (rL & 7);         // involution

  // ---- persistent state ----
  f32x4 creg[8];
#pragma unroll
  for (int mt = 0; mt < 8; ++mt)
#pragma unroll
    for (int r = 0; r < 4; ++r) {
      int n = n0 + wm * 128 + mt * 16 + kg * 4 + r;
      creg[mt][r] = c0[n * 512 + u];
    }
  f32x4 facc[2][2];
#pragma unroll
  for (int a = 0; a < 2; ++a)
#pragma unroll
    for (int b = 0; b < 2; ++b) facc[a][b] = (f32x4){0.f, 0.f, 0.f, 0.f};

  for (int i = 0; i <= TSTEPS; ++i) {
    const u16* hcur = (i & 1) ? hb1 : hb0;
    u16* hnxt = (i & 1) ? hb0 : hb1;

    if (i < TSTEPS) {
      // ================= LSTM step i: 256n x (4g x 64u), K=512, BK=64 =================
      f32x4 acc[8][4];
#pragma unroll
      for (int mt = 0; mt < 8; ++mt)
#pragma unroll
        for (int f = 0; f < 4; ++f) acc[mt][f] = (f32x4){0.f, 0.f, 0.f, 0.f};

      // prologue: stage K-tile 0 -> parity 0  (8 gloads/thread per tile)
#pragma unroll
      for (int qq = 0; qq < 4; ++qq) {
        int r = qq * 64 + rL;
        gload16(hcur + (n0 + r) * 512 + sw * 8, smem + qq * 4096 + wid * 512);
        gload16(Wp + (brow0 + r) * 512 + sw * 8, smem + 16384 + qq * 4096 + wid * 512);
      }
#pragma unroll 1
      for (int it = 0; it < 8; ++it) {
        if (it < 7) {
          const int kn = (it + 1) * 64;
          u16* dst = smem + ((it + 1) & 1) * 32768;
#pragma unroll
          for (int qq = 0; qq < 4; ++qq) {
            int r = qq * 64 + rL;
            gload16(hcur + (n0 + r) * 512 + kn + sw * 8, dst + qq * 4096 + wid * 512);
            gload16(Wp + (brow0 + r) * 512 + kn + sw * 8, dst + 16384 + qq * 4096 + wid * 512);
          }
          WAITV8();
        } else {
          WAITV0();
        }
        BAR();
        const u16* LA = smem + (it & 1) * 32768;
        const u16* LB = LA + 16384;
#pragma unroll
        for (int kk = 0; kk < 2; ++kk) {
          bf16x8 a[8], b[4];
#pragma unroll
          for (int mt = 0; mt < 8; ++mt) {
            int rr = wm * 128 + mt * 16 + jl;
            int cc = (kk * 4 + kg) ^ (rr & 7);
            a[mt] = *reinterpret_cast<const bf16x8*>(LA + rr * 64 + cc * 8);
          }
#pragma unroll
          for (int f = 0; f < 4; ++f) {
            int rr = wn * 64 + f * 16 + jl;
            int cc = (kk * 4 + kg) ^ (rr & 7);
            b[f] = *reinterpret_cast<const bf16x8*>(LB + rr * 64 + cc * 8);
          }
#pragma unroll
          for (int mt = 0; mt < 8; ++mt)
#pragma unroll
            for (int f = 0; f < 4; ++f) acc[mt][f] = MFMA16(a[mt], b[f], acc[mt][f]);
        }
        BAR();
      }

      // ---- activation epilogue (per-lane: all 4 gates of (n,u)) ----
      float eb[4], w0[4], w1[4];
#pragma unroll
      for (int f = 0; f < 4; ++f) {
        int j = f * 512 + u;
        eb[f] = bih[j] + bhh[j];
        w0[f] = Wih[j * 2 + 0];
        w1[f] = Wih[j * 2 + 1];
      }
#pragma unroll
      for (int mt = 0; mt < 8; ++mt)
#pragma unroll
        for (int r = 0; r < 4; ++r) {
          int n = n0 + wm * 128 + mt * 16 + kg * 4 + r;
          float x0 = x[n * 40 + i * 2 + 0];
          float x1 = x[n * 40 + i * 2 + 1];
          float gi = acc[mt][0][r] + eb[0] + x0 * w0[0] + x1 * w1[0];
          float gf = acc[mt][1][r] + eb[1] + x0 * w0[1] + x1 * w1[1];
          float gg2 = acc[mt][2][r] + eb[2] + x0 * w0[2] + x1 * w1[2];
          float go = acc[mt][3][r] + eb[3] + x0 * w0[3] + x1 * w1[3];
          float iv = sig_(gi), fv = sig_(gf), gv = tanh_(gg2), ov = sig_(go);
          float cn = fv * creg[mt][r] + iv * gv;
          creg[mt][r] = cn;
          hnxt[n * 512 + u] = f2bf(ov * tanh_(cn));
        }
    }

    if (i > 0) {
      // ================= FC1: 128m x 64j, K=1024, BK=64, t=i-1, A=h(i) ==========
      const int t = i - 1;
      // prologue: stage K-tile 0 -> parity 0 (3 gloads/thread per tile)
#pragma unroll
      for (int qq = 0; qq < 2; ++qq) {
        int r = qq * 64 + rL;
        gload16(hcur + (2 * (Fm0 + r)) * 512 + sw * 8, smem + qq * 4096 + wid * 512);
      }
      gload16(fc1w + (Fj0 + rL) * 20480 + t * 512 + sw * 8, smem + 8192 + wid * 512);
#pragma unroll 1
      for (int it = 0; it < 16; ++it) {
        if (it < 15) {
          const int kt = it + 1;
          const int an = kt >> 3, hcn = (kt & 7) * 64;
          u16* dst = smem + (kt & 1) * 32768;
#pragma unroll
          for (int qq = 0; qq < 2; ++qq) {
            int r = qq * 64 + rL;
            gload16(hcur + (2 * (Fm0 + r) + an) * 512 + hcn + sw * 8,
                    dst + qq * 4096 + wid * 512);
          }
          gload16(fc1w + (Fj0 + rL) * 20480 + an * 10240 + t * 512 + hcn + sw * 8,
                  dst + 8192 + wid * 512);
          WAITV3();
        } else {
          WAITV0();
        }
        BAR();
        const u16* LA = smem + (it & 1) * 32768;
        const u16* LBf = LA + 8192;
#pragma unroll
        for (int kk = 0; kk < 2; ++kk) {
          bf16x8 af[2], bf[2];
#pragma unroll
          for (int mf = 0; mf < 2; ++mf) {
            int rr = Fwm * 32 + mf * 16 + jl;
            int cc = (kk * 4 + kg) ^ (rr & 7);
            af[mf] = *reinterpret_cast<const bf16x8*>(LA + rr * 64 + cc * 8);
          }
#pragma unroll
          for (int jf = 0; jf < 2; ++jf) {
            int rr = Fwn * 32 + jf * 16 + jl;
            int cc = (kk * 4 + kg) ^ (rr & 7);
            bf[jf] = *reinterpret_cast<const bf16x8*>(LBf + rr * 64 + cc * 8);
          }
#pragma unroll
          for (int mf = 0; mf < 2; ++mf)
#pragma unroll
            for (int jf = 0; jf < 2; ++jf)
              facc[mf][jf] = MFMA16(af[mf], bf[jf], facc[mf][jf]);
        }
        BAR();
      }
    }

    // ---- per-group barrier: h(i+1) from this group's 8 blocks must be visible ----
    if (i < TSTEPS) {
      __syncthreads();
      if (tid == 0) {
        __threadfence();
        __hip_atomic_fetch_add(gcnt, 1, __ATOMIC_ACQ_REL, __HIP_MEMORY_SCOPE_AGENT);
        const int tgt = 8 * (i + 1);
        while (__hip_atomic_load(gcnt, __ATOMIC_ACQUIRE, __HIP_MEMORY_SCOPE_AGENT) < tgt)
          __builtin_amdgcn_s_sleep(2);
      }
      __syncthreads();
      __threadfence();
    }
  }

  // ---- write facc to global for head kernel ----
#pragma unroll
  for (int mf = 0; mf < 2; ++mf)
#pragma unroll
    for (int jf = 0; jf < 2; ++jf) {
      int j = Fj0 + Fwn * 32 + jf * 16 + jl;
#pragma unroll
      for (int r = 0; r < 4; ++r) {
        int m = Fm0 + Fwm * 32 + mf * 16 + kg * 4 + r;
        faccg[m * 512 + j] = facc[mf][jf][r];
      }
    }
}

// ---------------- head: relu(facc + b1) @ fc2^T + b2, sigmoid ----------------
__global__ __launch_bounds__(256) void head_kernel(
    const float* __restrict__ acc, const float* __restrict__ fc1b,
    const float* __restrict__ fc2w, const float* __restrict__ fc2b,
    float* __restrict__ out) {
  int lane = threadIdx.x & 63;
  int row = blockIdx.x * 4 + (threadIdx.x >> 6);
  float s = 0.f;
#pragma unroll
  for (int j = lane; j < 512; j += 64)
    s += fmaxf(acc[row * 512 + j] + fc1b[j], 0.f) * fc2w[j];
#pragma unroll
  for (int off = 32; off; off >>= 1) s += __shfl_down(s, off);
  if (lane == 0) out[row] = 1.f / (1.f + __expf(-(s + fc2b[0])));
}

extern "C" void kernel_launch(void* const* d_in, const int* in_sizes, int n_in,
                              void* d_out, int out_size, void* d_ws, size_t ws_size,
                              hipStream_t stream) {
  const float* x = (const float*)d_in[0];
  const float* h0 = (const float*)d_in[2];
  const float* c0 = (const float*)d_in[3];
  const float* Wih = (const float*)d_in[4];
  const float* Whh = (const float*)d_in[5];
  const float* bih = (const float*)d_in[6];
  const float* bhh = (const float*)d_in[7];
  const float* fc1w = (const float*)d_in[8];
  const float* fc1b = (const float*)d_in[9];
  const float* fc2w = (const float*)d_in[10];
  const float* fc2b = (const float*)d_in[11];
  float* out = (float*)d_out;

  char* ws = (char*)d_ws;
  const size_t MB = 1 << 20;
  u16* Whh_p = (u16*)(ws);               //  2 MB
  u16* fc1_bf = (u16*)(ws + 2 * MB);     // 20 MB
  u16* hbf0 = (u16*)(ws + 22 * MB);      //  8 MB
  u16* hbf1 = (u16*)(ws + 30 * MB);      //  8 MB
  float* facc = (float*)(ws + 38 * MB);  //  8 MB
  int* cnt = (int*)(ws + 46 * MB);       //  4 KB (32 groups x 128B)

  // allow 128 KB dynamic LDS (gfx950 has 160 KB/CU)
  hipFuncSetAttribute(reinterpret_cast<const void*>(lstm_persist),
                      hipFuncAttributeMaxDynamicSharedMemorySize, SMEM_BYTES);

  convert_whh_p<<<2048, 512, 0, stream>>>(Whh, Whh_p);
  convert_f32_bf16<<<10240, 256, 0, stream>>>(fc1w, fc1_bf, 512 * 20480);
  init_state<<<16384, 256, 0, stream>>>(h0, hbf0, cnt, 8192 * 512);

  lstm_persist<<<NBLK, 512, SMEM_BYTES, stream>>>(Whh_p, Wih, bih, bhh, x, c0,
                                                  hbf0, hbf1, fc1_bf, facc, cnt);
  head_kernel<<<1024, 256, 0, stream>>>(facc, fc1b, fc2w, fc2b, out);
}

// Round 7
// 880.969 us; speedup vs baseline: 2.4699x; 2.0193x over previous
//
#include <hip/hip_runtime.h>
#include <hip/hip_bf16.h>

#define HID 512
#define B2V 8192
#define TSTEPS 20

typedef __bf16 bf16x8 __attribute__((ext_vector_type(8)));
typedef float f32x4 __attribute__((ext_vector_type(4)));
typedef unsigned short u16;

__device__ __forceinline__ u16 f2bf(float f) {
  unsigned u = __builtin_bit_cast(unsigned, f);
  u = (u + 0x7FFFu + ((u >> 16) & 1u)) >> 16;   // RNE
  return (u16)u;
}
__device__ __forceinline__ float sig_(float v) { return 1.f / (1.f + __expf(-v)); }
__device__ __forceinline__ float tanh_(float v) { return 1.f - 2.f / (1.f + __expf(2.f * v)); }

#define MFMA16(a, b, c) __builtin_amdgcn_mfma_f32_16x16x32_bf16((a), (b), (c), 0, 0, 0)
#define BAR() asm volatile("s_barrier" ::: "memory")
#define WAITV0() asm volatile("s_waitcnt vmcnt(0)" ::: "memory")
#define WAITV8() asm volatile("s_waitcnt vmcnt(8)" ::: "memory")

// async global->LDS, 16B per lane. LDS dest is wave-uniform base + lane*16.
__device__ __forceinline__ void gload16(const u16* g, u16* lds) {
#if defined(__HIP_DEVICE_COMPILE__)
  __builtin_amdgcn_global_load_lds(
      (const __attribute__((address_space(1))) unsigned*)g,
      (__attribute__((address_space(3))) unsigned*)lds, 16, 0, 0);
#endif
}

// ---------------- prep kernels ----------------
__global__ void convert_f32_bf16(const float* __restrict__ s, u16* __restrict__ d, int n) {
  int i = (blockIdx.x * blockDim.x + threadIdx.x) * 4;
  if (i + 3 < n) {
    float4 v = *reinterpret_cast<const float4*>(s + i);
    ushort4 o;
    o.x = f2bf(v.x); o.y = f2bf(v.y); o.z = f2bf(v.z); o.w = f2bf(v.w);
    *reinterpret_cast<ushort4*>(d + i) = o;
  }
}

__global__ void init_state(const float* __restrict__ h0, const float* __restrict__ c0,
                           u16* __restrict__ hbf, float* __restrict__ cws,
                           float* __restrict__ acc, int n, int nacc) {
  int i = blockIdx.x * blockDim.x + threadIdx.x;
  if (i < n) { hbf[i] = f2bf(h0[i]); cws[i] = c0[i]; }
  if (i < nacc) acc[i] = 0.f;
}

// ---------------- fused step kernel ----------------
// blocks [0, nlstm): LSTM gates GEMM + activations for timestep t.
//   M=8192 x N=2048 (4 gates x 512 u), K=512. Block tile 128 x (4g x 32u).
// blocks [nlstm, ...): FC1 accumulation for timestep t-1 (reads same hin).
//   M=4096, N=512, K=1024. Block tile 128 x 128.
// K-loop: double-buffered LDS; per iter: stage(k+1) -> s_waitcnt vmcnt(8)
// (tile-k loads done, tile-k+1 loads stay in flight) -> s_barrier ->
// compute(k) -> s_barrier (protects buffer (k+1)&1 before next stage).
// XCD-pinned mapping (bid&7 heuristic): XCD x owns n-rows [1024x,1024x+1024)
// for lstm AND the matching fc1 m-rows.
__global__ __launch_bounds__(256, 2) void step_kernel(
    const u16* __restrict__ Whh,    // [2048][512] bf16
    const float* __restrict__ Wih,  // [2048][2]
    const float* __restrict__ bih, const float* __restrict__ bhh,
    const float* __restrict__ x,    // [8192][20][2] f32
    const u16* __restrict__ hin,    // [8192][512] bf16 (= h(t); fc1 A as [4096][1024])
    u16* __restrict__ hout,         // [8192][512] bf16 (= h(t+1))
    float* __restrict__ c,          // [8192][512] f32
    const u16* __restrict__ fc1w,   // [512][20480] bf16
    float* __restrict__ facc,       // [4096][512] f32
    int t, int nlstm) {
  __shared__ u16 smem[32768];       // 64 KB: 2 x (A[128][64] + B[128][64])

  const int tid = threadIdx.x;
  const int lane = tid & 63, wid = tid >> 6;
  const int jl = lane & 15, kg = lane >> 4;
  const int wm = wid >> 1, wn = wid & 1;
  const int srow = lane >> 3;                 // staging: row within 8-row call
  const int schunk = (lane & 7) ^ srow;       // pre-swizzled source chunk (involution)

  if ((int)blockIdx.x < nlstm) {
    // ================= LSTM gates =================
    const int bid = blockIdx.x;
    const int xcd = bid & 7, q8 = bid >> 3;   // XCD-pinned bijective remap (1024 = 8*128)
    const int n0 = (xcd * 8 + (q8 & 7)) * 128;
    const int u0 = (q8 >> 3) * 32;

    f32x4 acc[4][4];                          // [m-tile][gate]
#pragma unroll
    for (int i = 0; i < 4; ++i)
#pragma unroll
      for (int j = 0; j < 4; ++j) acc[i][j] = (f32x4){0.f, 0.f, 0.f, 0.f};

    // prologue: stage K-tile 0 -> buffer 0
#pragma unroll
    for (int q = 0; q < 4; ++q) {
      int r = (wid * 4 + q) * 8 + srow;
      gload16(hin + (n0 + r) * 512 + schunk * 8, smem + (wid * 4 + q) * 512);
    }
#pragma unroll
    for (int q = 0; q < 4; ++q) {
      int br = (wid * 4 + q) * 8 + srow;
      int g = br >> 5, ul = br & 31;
      gload16(Whh + (g * 512 + u0 + ul) * 512 + schunk * 8,
              smem + 8192 + (wid * 4 + q) * 512);
    }

#pragma unroll 1
    for (int ks = 0; ks < 8; ++ks) {
      if (ks < 7) {                           // stage K-tile ks+1 into other buffer
        u16* dst = smem + ((ks + 1) & 1) * 16384;
        const int kn = (ks + 1) * 64;
#pragma unroll
        for (int q = 0; q < 4; ++q) {
          int r = (wid * 4 + q) * 8 + srow;
          gload16(hin + (n0 + r) * 512 + kn + schunk * 8, dst + (wid * 4 + q) * 512);
        }
#pragma unroll
        for (int q = 0; q < 4; ++q) {
          int br = (wid * 4 + q) * 8 + srow;
          int g = br >> 5, ul = br & 31;
          gload16(Whh + (g * 512 + u0 + ul) * 512 + kn + schunk * 8,
                  dst + 8192 + (wid * 4 + q) * 512);
        }
        WAITV8();                             // tile ks landed; ks+1 stays in flight
      } else {
        WAITV0();
      }
      BAR();
      const u16* Acur = smem + (ks & 1) * 16384;
      const u16* Bcur = Acur + 8192;
#pragma unroll
      for (int kk = 0; kk < 2; ++kk) {
        const int cs = (kk * 4 + kg) ^ (jl & 7);
        bf16x8 a[4], b[4];
#pragma unroll
        for (int mt = 0; mt < 4; ++mt) {
          int row = wm * 64 + mt * 16 + jl;
          a[mt] = *reinterpret_cast<const bf16x8*>(Acur + row * 64 + cs * 8);
        }
#pragma unroll
        for (int g = 0; g < 4; ++g) {
          int br = g * 32 + wn * 16 + jl;
          b[g] = *reinterpret_cast<const bf16x8*>(Bcur + br * 64 + cs * 8);
        }
#pragma unroll
        for (int mt = 0; mt < 4; ++mt)
#pragma unroll
          for (int g = 0; g < 4; ++g) acc[mt][g] = MFMA16(a[mt], b[g], acc[mt][g]);
      }
      BAR();                                  // buffer (ks+1)&1 free for next stage
    }

    // ---- fused activation epilogue ----
    const int u = u0 + wn * 16 + jl;
    float eb[4], w0[4], w1[4];
#pragma unroll
    for (int g = 0; g < 4; ++g) {
      int j = g * 512 + u;
      eb[g] = bih[j] + bhh[j];
      w0[g] = Wih[j * 2 + 0];
      w1[g] = Wih[j * 2 + 1];
    }
#pragma unroll
    for (int mt = 0; mt < 4; ++mt) {
#pragma unroll
      for (int r = 0; r < 4; ++r) {
        int n = n0 + wm * 64 + mt * 16 + kg * 4 + r;
        float x0 = x[n * 40 + t * 2 + 0];
        float x1 = x[n * 40 + t * 2 + 1];
        float gi = acc[mt][0][r] + eb[0] + x0 * w0[0] + x1 * w1[0];
        float gf = acc[mt][1][r] + eb[1] + x0 * w0[1] + x1 * w1[1];
        float gg = acc[mt][2][r] + eb[2] + x0 * w0[2] + x1 * w1[2];
        float go = acc[mt][3][r] + eb[3] + x0 * w0[3] + x1 * w1[3];
        float iv = sig_(gi), fv = sig_(gf), gv = tanh_(gg), ov = sig_(go);
        int idx = n * 512 + u;
        float cn = fv * c[idx] + iv * gv;
        c[idx] = cn;
        hout[idx] = f2bf(ov * tanh_(cn));
      }
    }
  } else {
    // ================= FC1 accumulate (timestep t-1) =================
    const int bid = blockIdx.x - nlstm;       // 0..127
    const int ft = t - 1;
    const int xcd = bid & 7, q8 = bid >> 3;   // XCD-pinned bijective remap (128 = 8*16)
    const int m0 = (xcd * 4 + (q8 & 3)) * 128;
    const int j0 = (q8 >> 2) * 128;

    f32x4 acc[4][4];                          // [m-tile][n-tile]
#pragma unroll
    for (int i = 0; i < 4; ++i)
#pragma unroll
      for (int j = 0; j < 4; ++j) acc[i][j] = (f32x4){0.f, 0.f, 0.f, 0.f};

    // prologue: stage K-tile 0 -> buffer 0
#pragma unroll
    for (int q = 0; q < 4; ++q) {
      int r = (wid * 4 + q) * 8 + srow;
      gload16(hin + (m0 + r) * 1024 + schunk * 8, smem + (wid * 4 + q) * 512);
    }
    {
      const int colb0 = ft * 512 + schunk * 8;
#pragma unroll
      for (int q = 0; q < 4; ++q) {
        int br = (wid * 4 + q) * 8 + srow;
        gload16(fc1w + (j0 + br) * 20480 + colb0, smem + 8192 + (wid * 4 + q) * 512);
      }
    }

#pragma unroll 1
    for (int ks = 0; ks < 16; ++ks) {
      if (ks < 15) {
        u16* dst = smem + ((ks + 1) & 1) * 16384;
        const int kn = (ks + 1) * 64;
#pragma unroll
        for (int q = 0; q < 4; ++q) {
          int r = (wid * 4 + q) * 8 + srow;
          gload16(hin + (m0 + r) * 1024 + kn + schunk * 8, dst + (wid * 4 + q) * 512);
        }
        const int colb = ((kn >> 9) * 10240) + ft * 512 + (kn & 511) + schunk * 8;
#pragma unroll
        for (int q = 0; q < 4; ++q) {
          int br = (wid * 4 + q) * 8 + srow;
          gload16(fc1w + (j0 + br) * 20480 + colb, dst + 8192 + (wid * 4 + q) * 512);
        }
        WAITV8();
      } else {
        WAITV0();
      }
      BAR();
      const u16* Acur = smem + (ks & 1) * 16384;
      const u16* Bcur = Acur + 8192;
#pragma unroll
      for (int kk = 0; kk < 2; ++kk) {
        const int cs = (kk * 4 + kg) ^ (jl & 7);
        bf16x8 a[4], b[4];
#pragma unroll
        for (int mt = 0; mt < 4; ++mt) {
          int row = wm * 64 + mt * 16 + jl;
          a[mt] = *reinterpret_cast<const bf16x8*>(Acur + row * 64 + cs * 8);
        }
#pragma unroll
        for (int nt = 0; nt < 4; ++nt) {
          int br = wn * 64 + nt * 16 + jl;
          b[nt] = *reinterpret_cast<const bf16x8*>(Bcur + br * 64 + cs * 8);
        }
#pragma unroll
        for (int mt = 0; mt < 4; ++mt)
#pragma unroll
          for (int nt = 0; nt < 4; ++nt) acc[mt][nt] = MFMA16(a[mt], b[nt], acc[mt][nt]);
      }
      BAR();
    }
#pragma unroll
    for (int mt = 0; mt < 4; ++mt)
#pragma unroll
      for (int nt = 0; nt < 4; ++nt) {
        int j = j0 + wn * 64 + nt * 16 + jl;
#pragma unroll
        for (int r = 0; r < 4; ++r) {
          int bb = m0 + wm * 64 + mt * 16 + kg * 4 + r;
          facc[bb * 512 + j] += acc[mt][nt][r];
        }
      }
  }
}

// ---------------- head: relu(acc + b1) @ fc2^T + b2, sigmoid ----------------
__global__ __launch_bounds__(256) void head_kernel(
    const float* __restrict__ acc, const float* __restrict__ fc1b,
    const float* __restrict__ fc2w, const float* __restrict__ fc2b,
    float* __restrict__ out) {
  int lane = threadIdx.x & 63;
  int row = blockIdx.x * 4 + (threadIdx.x >> 6);
  float s = 0.f;
#pragma unroll
  for (int j = lane; j < 512; j += 64)
    s += fmaxf(acc[row * 512 + j] + fc1b[j], 0.f) * fc2w[j];
#pragma unroll
  for (int off = 32; off; off >>= 1) s += __shfl_down(s, off);
  if (lane == 0) out[row] = 1.f / (1.f + __expf(-(s + fc2b[0])));
}

extern "C" void kernel_launch(void* const* d_in, const int* in_sizes, int n_in,
                              void* d_out, int out_size, void* d_ws, size_t ws_size,
                              hipStream_t stream) {
  const float* x = (const float*)d_in[0];
  const float* h0 = (const float*)d_in[2];
  const float* c0 = (const float*)d_in[3];
  const float* Wih = (const float*)d_in[4];
  const float* Whh = (const float*)d_in[5];
  const float* bih = (const float*)d_in[6];
  const float* bhh = (const float*)d_in[7];
  const float* fc1w = (const float*)d_in[8];
  const float* fc1b = (const float*)d_in[9];
  const float* fc2w = (const float*)d_in[10];
  const float* fc2b = (const float*)d_in[11];
  float* out = (float*)d_out;

  char* ws = (char*)d_ws;
  const size_t MB = 1 << 20;
  u16* Whh_bf = (u16*)(ws);              //  2 MB
  u16* fc1_bf = (u16*)(ws + 2 * MB);     // 20 MB
  u16* hbf0 = (u16*)(ws + 22 * MB);      //  8 MB
  u16* hbf1 = (u16*)(ws + 30 * MB);      //  8 MB
  float* cws = (float*)(ws + 38 * MB);   // 16 MB
  float* facc = (float*)(ws + 54 * MB);  //  8 MB

  convert_f32_bf16<<<1024, 256, 0, stream>>>(Whh, Whh_bf, 2048 * 512);
  convert_f32_bf16<<<10240, 256, 0, stream>>>(fc1w, fc1_bf, 512 * 20480);
  init_state<<<16384, 256, 0, stream>>>(h0, c0, hbf0, cws, facc, B2V * HID, 4096 * HID);

  u16* hb[2] = {hbf0, hbf1};
  for (int t = 0; t < TSTEPS; ++t) {
    int grid = 1024 + (t > 0 ? 128 : 0);
    step_kernel<<<grid, 256, 0, stream>>>(Whh_bf, Wih, bih, bhh, x,
                                          hb[t & 1], hb[(t + 1) & 1], cws,
                                          fc1_bf, facc, t, 1024);
  }
  // final fc1 for t=19 reads hb[20&1] = hb[0]
  step_kernel<<<128, 256, 0, stream>>>(Whh_bf, Wih, bih, bhh, x,
                                       hb[0], hb[1], cws, fc1_bf, facc, 20, 0);
  head_kernel<<<1024, 256, 0, stream>>>(facc, fc1b, fc2w, fc2b, out);
}

// Round 9
// 632.518 us; speedup vs baseline: 3.4401x; 1.3928x over previous
//
#include <hip/hip_runtime.h>
#include <hip/hip_bf16.h>

#define TSTEPS 20
#define SMEM_BYTES 131072

typedef __bf16 bf16x8 __attribute__((ext_vector_type(8)));
typedef float f32x4 __attribute__((ext_vector_type(4)));
typedef unsigned short u16;

__device__ __forceinline__ u16 f2bf(float f) {
  unsigned u = __builtin_bit_cast(unsigned, f);
  u = (u + 0x7FFFu + ((u >> 16) & 1u)) >> 16;  // RNE
  return (u16)u;
}
__device__ __forceinline__ float rcp_(float v) { return __builtin_amdgcn_rcpf(v); }
__device__ __forceinline__ float sig_(float v) { return rcp_(1.f + __expf(-v)); }
__device__ __forceinline__ float tanh_(float v) { return 1.f - 2.f * rcp_(1.f + __expf(2.f * v)); }

#define MFMA16(a, b, c) __builtin_amdgcn_mfma_f32_16x16x32_bf16((a), (b), (c), 0, 0, 0)
#define BAR() asm volatile("s_barrier" ::: "memory")
#define WAITV(n) asm volatile("s_waitcnt vmcnt(" #n ")" ::: "memory")
#define WAITLG() asm volatile("s_waitcnt lgkmcnt(0)" ::: "memory")

__device__ __forceinline__ void gload16(const u16* g, u16* lds) {
#if defined(__HIP_DEVICE_COMPILE__)
  __builtin_amdgcn_global_load_lds(
      (const __attribute__((address_space(1))) unsigned*)g,
      (__attribute__((address_space(3))) unsigned*)lds, 16, 0, 0);
#endif
}

// ---------------- prep kernels ----------------
__global__ void convert_f32_bf16(const float* __restrict__ s, u16* __restrict__ d, int n) {
  int i = (blockIdx.x * blockDim.x + threadIdx.x) * 4;
  if (i + 3 < n) {
    float4 v = *reinterpret_cast<const float4*>(s + i);
    ushort4 o;
    o.x = f2bf(v.x); o.y = f2bf(v.y); o.z = f2bf(v.z); o.w = f2bf(v.w);
    *reinterpret_cast<ushort4*>(d + i) = o;
  }
}

// permuted Whh: p = s*256 + w*64 + f*16 + j  <-  orig row f*512 + s*64 + w*16 + j
__global__ void convert_whh_p(const float* __restrict__ w, u16* __restrict__ d) {
  int p = blockIdx.x;         // 2048 rows
  int k = threadIdx.x;        // 512 cols
  int j = p & 15, f = (p >> 4) & 3, wg = (p >> 6) & 3, s = p >> 8;
  int orig = (f << 9) + (s << 6) + (wg << 4) + j;
  d[p * 512 + k] = f2bf(w[orig * 512 + k]);
}

// augmented-B: Bx[p][0..31] = [Wih[o][0], Wih[o][1], bih[o]+bhh[o], 0...]
__global__ void bx_prep(const float* __restrict__ Wih, const float* __restrict__ bih,
                        const float* __restrict__ bhh, u16* __restrict__ Bx) {
  int p = blockIdx.x * blockDim.x + threadIdx.x;
  if (p >= 2048) return;
  int j = p & 15, f = (p >> 4) & 3, wg = (p >> 6) & 3, s = p >> 8;
  int o = (f << 9) + (s << 6) + (wg << 4) + j;
  u16* row = Bx + p * 32;
  row[0] = f2bf(Wih[o * 2 + 0]);
  row[1] = f2bf(Wih[o * 2 + 1]);
  row[2] = f2bf(bih[o] + bhh[o]);
#pragma unroll
  for (int k = 3; k < 32; ++k) row[k] = 0;
}

__global__ void init_state(const float* __restrict__ h0, const float* __restrict__ c0,
                           u16* __restrict__ hbf, float* __restrict__ cws,
                           float* __restrict__ acc, int n, int nacc) {
  int i = blockIdx.x * blockDim.x + threadIdx.x;
  if (i < n) { hbf[i] = f2bf(h0[i]); cws[i] = c0[i]; }
  if (i < nacc) acc[i] = 0.f;
}

// ---------------- fused step kernel: 256 blocks x 512 threads, 1 block/CU ----
// LSTM step t: block tile 256n x 256pc (4 gates x 64 u), K=512+aug32, BK=64.
//   8 waves 2M x 4N -> per-wave 128n x (4g x 16u), acc[8][4] frags.
// FC1 (t-1): block tile 128m x 64j, K=1024, BK=64; 8 waves 4M x 2N.
// Both read the same hin rows [nb*256, +256). XCD-bijective: bid&7 = xcd,
// nb = (bid&7)*4 + (bid>>6), s = (bid>>3)&7 -> each XCD owns 4 n-groups.
__global__ __launch_bounds__(512, 1) void step256(
    const u16* __restrict__ Wp,     // [2048][512] perm bf16
    const u16* __restrict__ Bxg,    // [2048][32] aug B
    const float* __restrict__ x,    // [8192][20][2] f32
    const u16* __restrict__ hin,    // [8192][512] bf16 = h(t)
    u16* __restrict__ hout,         // h(t+1)
    float* __restrict__ c,          // [8192][512] f32
    const u16* __restrict__ fc1w,   // [512][20480] bf16
    float* __restrict__ facc,       // [4096][512] f32
    int t, int doLstm, int doFc1) {
  extern __shared__ char S[];       // 128 KB: p*65536 + {A:0..32K, B:32K..64K}

  const int tid = threadIdx.x;
  const int lane = tid & 63, wid = tid >> 6;
  const int jl = lane & 15, kg = lane >> 4;
  const int bid = blockIdx.x;
  const int s = (bid >> 3) & 7;
  const int nb = (bid & 7) * 4 + (bid >> 6);
  const int n0 = nb * 256;
  // staging map: 64 rows/round, 8x16B chunks, XOR involution
  const int srow = tid >> 3;
  const int sw = (tid & 7) ^ (srow & 7);

  if (doLstm) {
    const int wm = wid >> 2, wn = wid & 3;
    const int u = s * 64 + wn * 16 + jl;
    // per-lane LDS read byte-bases (kk = 0,1)
    const int swz0 = (kg ^ (jl & 7)) * 16;
    const int swz1 = ((4 + kg) ^ (jl & 7)) * 16;
    const int aB0 = wm * 16384 + jl * 128 + swz0;
    const int aB1 = wm * 16384 + jl * 128 + swz1;
    const int bB0 = 32768 + wn * 8192 + jl * 128 + swz0;
    const int bB1 = 32768 + wn * 8192 + jl * 128 + swz1;
    const u16* srcA = hin + (n0 + srow) * 512 + sw * 8;
    const u16* srcB = Wp + (s * 256 + srow) * 512 + sw * 8;

    f32x4 acc[8][4];
#pragma unroll
    for (int mt = 0; mt < 8; ++mt)
#pragma unroll
      for (int f = 0; f < 4; ++f) acc[mt][f] = (f32x4){0.f, 0.f, 0.f, 0.f};

    // ---- prologue: x load, Bx stage (->p0 B slot), tile0 stage (->p1) ----
    float2 xv = {0.f, 0.f};
    if (tid < 256) xv = *reinterpret_cast<const float2*>(x + (n0 + tid) * 40 + t * 2);
    {
      const int r0 = tid >> 2, ch = tid & 3;  // Bx: 256 rows x 64B, 2 rounds of 128 rows
      gload16(Bxg + (s * 256 + 0 * 128 + r0) * 32 + ch * 8, (u16*)(S + 32768 + 0 * 8192 + wid * 1024));
      gload16(Bxg + (s * 256 + 1 * 128 + r0) * 32 + ch * 8, (u16*)(S + 32768 + 1 * 8192 + wid * 1024));
    }
#pragma unroll
    for (int q = 0; q < 4; ++q) {
      gload16(srcA + q * 32768, (u16*)(S + 65536 + q * 8192 + wid * 1024));
      gload16(srcB + q * 32768, (u16*)(S + 65536 + 32768 + q * 8192 + wid * 1024));
    }
    // build Ax rows [x0,x1,1,0...] in p0 A slot (compiler waits xv exactly)
    if (tid < 256) {
      u16 row0[8] = {f2bf(xv.x), f2bf(xv.y), 0x3F80u, 0, 0, 0, 0, 0};
      *reinterpret_cast<uint4*>(S + tid * 64) = *reinterpret_cast<const uint4*>(row0);
      uint4 z = {0u, 0u, 0u, 0u};
      *reinterpret_cast<uint4*>(S + tid * 64 + 16) = z;
      *reinterpret_cast<uint4*>(S + tid * 64 + 32) = z;
      *reinterpret_cast<uint4*>(S + tid * 64 + 48) = z;
    }
    WAITLG();
    WAITV(8);   // Bx (+x) drained; tile0's 8 still in flight
    BAR();
    // ---- aug phase (K=32): gates += x@Wih^T + biases (linear LDS, one-shot) ----
    {
#pragma unroll
      for (int mt = 0; mt < 8; ++mt) {
        bf16x8 a = *reinterpret_cast<const bf16x8*>(S + (wm * 128 + mt * 16 + jl) * 64 + kg * 16);
#pragma unroll
        for (int f = 0; f < 4; ++f) {
          bf16x8 b = *reinterpret_cast<const bf16x8*>(S + 32768 + (wn * 64 + f * 16 + jl) * 64 + kg * 16);
          acc[mt][f] = MFMA16(a, b, acc[mt][f]);
        }
      }
    }
    BAR();

    // ---- main K-loop: 8 tiles, tile kt lives at parity !(kt&1) ----
#define LSTAGE(kt, p)                                                              \
  do {                                                                             \
    _Pragma("unroll") for (int q = 0; q < 4; ++q) {                                \
      gload16(srcA + q * 32768 + (kt) * 64, (u16*)(S + (p) * 65536 + q * 8192 + wid * 1024)); \
      gload16(srcB + q * 32768 + (kt) * 64, (u16*)(S + (p) * 65536 + 32768 + q * 8192 + wid * 1024)); \
    }                                                                              \
  } while (0)
#define LCOMP(p)                                                                   \
  do {                                                                             \
    bf16x8 a0[8], b0[4];                                                           \
    _Pragma("unroll") for (int mt = 0; mt < 8; ++mt)                               \
        a0[mt] = *reinterpret_cast<const bf16x8*>(S + (p) * 65536 + aB0 + mt * 2048); \
    _Pragma("unroll") for (int f = 0; f < 4; ++f)                                  \
        b0[f] = *reinterpret_cast<const bf16x8*>(S + (p) * 65536 + bB0 + f * 2048); \
    _Pragma("unroll") for (int mt = 0; mt < 8; ++mt)                               \
      _Pragma("unroll") for (int f = 0; f < 4; ++f)                                \
        acc[mt][f] = MFMA16(a0[mt], b0[f], acc[mt][f]);                            \
    _Pragma("unroll") for (int mt = 0; mt < 8; ++mt)                               \
        a0[mt] = *reinterpret_cast<const bf16x8*>(S + (p) * 65536 + aB1 + mt * 2048); \
    _Pragma("unroll") for (int f = 0; f < 4; ++f)                                  \
        b0[f] = *reinterpret_cast<const bf16x8*>(S + (p) * 65536 + bB1 + f * 2048); \
    _Pragma("unroll") for (int mt = 0; mt < 8; ++mt)                               \
      _Pragma("unroll") for (int f = 0; f < 4; ++f)                                \
        acc[mt][f] = MFMA16(a0[mt], b0[f], acc[mt][f]);                            \
  } while (0)

#pragma unroll
    for (int kt = 0; kt < 8; ++kt) {
      if (kt < 7) {
        if ((kt + 1) & 1) LSTAGE(kt + 1, 0); else LSTAGE(kt + 1, 1);
        WAITV(8);
      } else {
        WAITV(0);
      }
      BAR();
      if (kt & 1) LCOMP(0); else LCOMP(1);
      BAR();
    }

    // ---- activation epilogue: gates are complete in acc ----
    float cv[8][4];
#pragma unroll
    for (int mt = 0; mt < 8; ++mt)
#pragma unroll
      for (int r = 0; r < 4; ++r)
        cv[mt][r] = c[(n0 + wm * 128 + mt * 16 + kg * 4 + r) * 512 + u];
#pragma unroll
    for (int mt = 0; mt < 8; ++mt)
#pragma unroll
      for (int r = 0; r < 4; ++r) {
        int n = n0 + wm * 128 + mt * 16 + kg * 4 + r;
        float iv = sig_(acc[mt][0][r]);
        float fv = sig_(acc[mt][1][r]);
        float gv = tanh_(acc[mt][2][r]);
        float ov = sig_(acc[mt][3][r]);
        float cn = fv * cv[mt][r] + iv * gv;
        c[n * 512 + u] = cn;
        hout[n * 512 + u] = f2bf(ov * tanh_(cn));
      }
  }

  if (doFc1) {
    // ================= FC1 for t-1: A = hin, tile 128m x 64j, K=1024 ===========
    const int Fm0 = nb * 128, Fj0 = s * 64;
    const int Fwm = wid >> 1, Fwn = wid & 1;
    const int tf = t - 1;
    const int swz0 = (kg ^ (jl & 7)) * 16;
    const int swz1 = ((4 + kg) ^ (jl & 7)) * 16;
    const int faB0 = Fwm * 4096 + jl * 128 + swz0;
    const int faB1 = Fwm * 4096 + jl * 128 + swz1;
    const int fbB0 = 16384 + Fwn * 4096 + jl * 128 + swz0;
    const int fbB1 = 16384 + Fwn * 4096 + jl * 128 + swz1;
    const u16* fsrcA = hin + 2 * (Fm0 + srow) * 512 + sw * 8;   // +q*65536 +an*512 +(kt&7)*64
    const u16* fsrcB = fc1w + (Fj0 + srow) * 20480 + tf * 512 + sw * 8;

    f32x4 fa[2][2];
#pragma unroll
    for (int a = 0; a < 2; ++a)
#pragma unroll
      for (int b = 0; b < 2; ++b) fa[a][b] = (f32x4){0.f, 0.f, 0.f, 0.f};

#define FSTAGE(kt, p)                                                              \
  do {                                                                             \
    const int an_ = (kt) >> 3, kc_ = ((kt) & 7) * 64;                              \
    gload16(fsrcA + 0 * 65536 + an_ * 512 + kc_, (u16*)(S + (p) * 32768 + 0 * 8192 + wid * 1024)); \
    gload16(fsrcA + 1 * 65536 + an_ * 512 + kc_, (u16*)(S + (p) * 32768 + 1 * 8192 + wid * 1024)); \
    gload16(fsrcB + an_ * 10240 + kc_, (u16*)(S + (p) * 32768 + 16384 + wid * 1024)); \
  } while (0)
#define FCOMP(p)                                                                   \
  do {                                                                             \
    bf16x8 af[2], bf[2];                                                           \
    _Pragma("unroll") for (int mf = 0; mf < 2; ++mf)                               \
        af[mf] = *reinterpret_cast<const bf16x8*>(S + (p) * 32768 + faB0 + mf * 2048); \
    _Pragma("unroll") for (int jf = 0; jf < 2; ++jf)                               \
        bf[jf] = *reinterpret_cast<const bf16x8*>(S + (p) * 32768 + fbB0 + jf * 2048); \
    _Pragma("unroll") for (int mf = 0; mf < 2; ++mf)                               \
      _Pragma("unroll") for (int jf = 0; jf < 2; ++jf)                             \
        fa[mf][jf] = MFMA16(af[mf], bf[jf], fa[mf][jf]);                           \
    _Pragma("unroll") for (int mf = 0; mf < 2; ++mf)                               \
        af[mf] = *reinterpret_cast<const bf16x8*>(S + (p) * 32768 + faB1 + mf * 2048); \
    _Pragma("unroll") for (int jf = 0; jf < 2; ++jf)                               \
        bf[jf] = *reinterpret_cast<const bf16x8*>(S + (p) * 32768 + fbB1 + jf * 2048); \
    _Pragma("unroll") for (int mf = 0; mf < 2; ++mf)                               \
      _Pragma("unroll") for (int jf = 0; jf < 2; ++jf)                             \
        fa[mf][jf] = MFMA16(af[mf], bf[jf], fa[mf][jf]);                           \
  } while (0)

    FSTAGE(0, 0);
#pragma unroll
    for (int kt = 0; kt < 16; ++kt) {
      if (kt < 15) {
        if ((kt + 1) & 1) FSTAGE(kt + 1, 1); else FSTAGE(kt + 1, 0);
        WAITV(3);
      } else {
        WAITV(0);
      }
      BAR();
      if (kt & 1) FCOMP(1); else FCOMP(0);
      BAR();
    }
#pragma unroll
    for (int mf = 0; mf < 2; ++mf)
#pragma unroll
      for (int jf = 0; jf < 2; ++jf) {
        int j = Fj0 + Fwn * 32 + jf * 16 + jl;
#pragma unroll
        for (int r = 0; r < 4; ++r) {
          int m = Fm0 + Fwm * 32 + mf * 16 + kg * 4 + r;
          facc[m * 512 + j] += fa[mf][jf][r];
        }
      }
  }
}

// ---------------- head: relu(facc + b1) @ fc2^T + b2, sigmoid ----------------
__global__ __launch_bounds__(256) void head_kernel(
    const float* __restrict__ acc, const float* __restrict__ fc1b,
    const float* __restrict__ fc2w, const float* __restrict__ fc2b,
    float* __restrict__ out) {
  int lane = threadIdx.x & 63;
  int row = blockIdx.x * 4 + (threadIdx.x >> 6);
  float sum = 0.f;
#pragma unroll
  for (int j = lane; j < 512; j += 64)
    sum += fmaxf(acc[row * 512 + j] + fc1b[j], 0.f) * fc2w[j];
#pragma unroll
  for (int off = 32; off; off >>= 1) sum += __shfl_down(sum, off);
  if (lane == 0) out[row] = sig_(sum + fc2b[0]);
}

extern "C" void kernel_launch(void* const* d_in, const int* in_sizes, int n_in,
                              void* d_out, int out_size, void* d_ws, size_t ws_size,
                              hipStream_t stream) {
  const float* x = (const float*)d_in[0];
  const float* h0 = (const float*)d_in[2];
  const float* c0 = (const float*)d_in[3];
  const float* Wih = (const float*)d_in[4];
  const float* Whh = (const float*)d_in[5];
  const float* bih = (const float*)d_in[6];
  const float* bhh = (const float*)d_in[7];
  const float* fc1w = (const float*)d_in[8];
  const float* fc1b = (const float*)d_in[9];
  const float* fc2w = (const float*)d_in[10];
  const float* fc2b = (const float*)d_in[11];
  float* out = (float*)d_out;

  char* ws = (char*)d_ws;
  const size_t MB = 1 << 20;
  u16* Wp = (u16*)(ws);                  //  2 MB
  u16* fc1_bf = (u16*)(ws + 2 * MB);     // 20 MB
  u16* hbf0 = (u16*)(ws + 22 * MB);      //  8 MB
  u16* hbf1 = (u16*)(ws + 30 * MB);      //  8 MB
  float* cws = (float*)(ws + 38 * MB);   // 16 MB
  float* facc = (float*)(ws + 54 * MB);  //  8 MB
  u16* Bxg = (u16*)(ws + 62 * MB);       // 128 KB

  (void)hipFuncSetAttribute(reinterpret_cast<const void*>(step256),
                            hipFuncAttributeMaxDynamicSharedMemorySize, SMEM_BYTES);

  convert_whh_p<<<2048, 512, 0, stream>>>(Whh, Wp);
  bx_prep<<<8, 256, 0, stream>>>(Wih, bih, bhh, Bxg);
  convert_f32_bf16<<<10240, 256, 0, stream>>>(fc1w, fc1_bf, 512 * 20480);
  init_state<<<16384, 256, 0, stream>>>(h0, c0, hbf0, cws, facc, 8192 * 512, 4096 * 512);

  u16* hb[2] = {hbf0, hbf1};
  for (int t = 0; t <= TSTEPS; ++t) {
    step256<<<256, 512, SMEM_BYTES, stream>>>(
        Wp, Bxg, x, hb[t & 1], hb[(t + 1) & 1], cws, fc1_bf, facc,
        t, t < TSTEPS ? 1 : 0, t > 0 ? 1 : 0);
  }
  head_kernel<<<1024, 256, 0, stream>>>(facc, fc1b, fc2w, fc2b, out);
}